// Round 10
// baseline (112.111 us; speedup 1.0000x reference)
//
#include <hip/hip_runtime.h>
#include <hip/hip_fp16.h>
#include <math.h>

#define DIMN (1 << 20)   // 2^20 per batch row
// d_out: [2][16][DIMN] f32.  d_ws: [16][DIMN] half2(re,im) interleaved (64 MiB).
// H·D(t)·H = (H_l·D_l·H_l) ⊗ (H_h·D_h·H_h):  popc(i)=popc(l)+popc(h) -> D = D_l⊗D_h.
// Pass A: low-bit operator along contiguous rows.  Pass B: high-bit operator, LDS-transposed tile.

typedef unsigned int uint2v __attribute__((ext_vector_type(2)));

// ---------------- bit-cast helpers ----------------
__device__ __forceinline__ unsigned int h2u(__half2 v){ union{__half2 h; unsigned int u;} x; x.h=v; return x.u; }
__device__ __forceinline__ __half2 u2h(unsigned int v){ union{unsigned int u; __half2 h;} x; x.u=v; return x.h; }

__device__ __forceinline__ void bf(float& a, float& b) { float s = a + b; b = a - b; a = s; }

// ---------------- DPP lane-exchange (VALU pipe, not DS) ----------------
template<int CTRL>
__device__ __forceinline__ float dppf(float x) {
    return __int_as_float(__builtin_amdgcn_mov_dpp(__float_as_int(x), CTRL, 0xF, 0xF, true));
}
template<int CTRL>
__device__ __forceinline__ unsigned int dppu(unsigned int x) {
    return (unsigned int)__builtin_amdgcn_mov_dpp((int)x, CTRL, 0xF, 0xF, true);
}
__device__ __forceinline__ float xor4_f(float x) { return dppf<0x1B>(dppf<0x141>(x)); }
__device__ __forceinline__ unsigned int xor4_u(unsigned int x) { return dppu<0x1B>(dppu<0x141>(x)); }

// ---------------- permlane swap butterflies (VALU pipe) ----------------
__device__ __forceinline__ float bfly16_f(float x, float sgn) {
#if __has_builtin(__builtin_amdgcn_permlane16_swap)
    uint2v r = __builtin_amdgcn_permlane16_swap(__float_as_uint(x), __float_as_uint(x), false, false);
    return fmaf(sgn, __uint_as_float(r.y), __uint_as_float(r.x));
#else
    float p = __shfl_xor(x, 16);
    return fmaf(sgn, x, p);
#endif
}
__device__ __forceinline__ float bfly32_f(float x, float sgn) {
#if __has_builtin(__builtin_amdgcn_permlane32_swap)
    uint2v r = __builtin_amdgcn_permlane32_swap(__float_as_uint(x), __float_as_uint(x), false, false);
    return fmaf(sgn, __uint_as_float(r.y), __uint_as_float(r.x));
#else
    float p = __shfl_xor(x, 32);
    return fmaf(sgn, x, p);
#endif
}
__device__ __forceinline__ __half2 bfly16_h2(__half2 x, __half2 sgn) {
#if __has_builtin(__builtin_amdgcn_permlane16_swap)
    uint2v r = __builtin_amdgcn_permlane16_swap(h2u(x), h2u(x), false, false);
    return __hfma2(u2h(r.y), sgn, u2h(r.x));
#else
    __half2 p = u2h((unsigned)__shfl_xor((int)h2u(x), 16));
    return __hfma2(x, sgn, p);
#endif
}
__device__ __forceinline__ __half2 bfly32_h2(__half2 x, __half2 sgn) {
#if __has_builtin(__builtin_amdgcn_permlane32_swap)
    uint2v r = __builtin_amdgcn_permlane32_swap(h2u(x), h2u(x), false, false);
    return __hfma2(u2h(r.y), sgn, u2h(r.x));
#else
    __half2 p = u2h((unsigned)__shfl_xor((int)h2u(x), 32));
    return __hfma2(x, sgn, p);
#endif
}

// ---------------- f32 WHT over 10 bits (all-VALU lane exchange) ----------------
__device__ __forceinline__ void wht16_f32(float v[16], int lane) {
    #pragma unroll
    for (int s = 1; s < 16; s <<= 1)
        #pragma unroll
        for (int r = 0; r < 16; r++)
            if (!(r & s)) bf(v[r], v[r ^ s]);
    {   float sgn = (lane & 1) ? -1.0f : 1.0f;
        #pragma unroll
        for (int r = 0; r < 16; r++) { float p = dppf<0xB1>(v[r]); v[r] = fmaf(sgn, v[r], p); } }
    {   float sgn = (lane & 2) ? -1.0f : 1.0f;
        #pragma unroll
        for (int r = 0; r < 16; r++) { float p = dppf<0x4E>(v[r]); v[r] = fmaf(sgn, v[r], p); } }
    {   float sgn = (lane & 4) ? -1.0f : 1.0f;
        #pragma unroll
        for (int r = 0; r < 16; r++) { float p = xor4_f(v[r]); v[r] = fmaf(sgn, v[r], p); } }
    {   float sgn = (lane & 8) ? -1.0f : 1.0f;
        #pragma unroll
        for (int r = 0; r < 16; r++) { float p = dppf<0x128>(v[r]); v[r] = fmaf(sgn, v[r], p); } }
    {   float sgn = (lane & 16) ? -1.0f : 1.0f;
        #pragma unroll
        for (int r = 0; r < 16; r++) v[r] = bfly16_f(v[r], sgn); }
    {   float sgn = (lane & 32) ? -1.0f : 1.0f;
        #pragma unroll
        for (int r = 0; r < 16; r++) v[r] = bfly32_f(v[r], sgn); }
}

// ---------------- half2 (re,im)-packed WHT over 10 bits ----------------
__device__ __forceinline__ void wht16_h2(__half2 v[16], int lane) {
    #pragma unroll
    for (int s = 1; s < 16; s <<= 1)
        #pragma unroll
        for (int r = 0; r < 16; r++)
            if (!(r & s)) {
                __half2 t = __hadd2(v[r], v[r ^ s]);
                v[r ^ s]  = __hsub2(v[r], v[r ^ s]);
                v[r] = t;
            }
    {   __half2 sgn = __float2half2_rn((lane & 1) ? -1.0f : 1.0f);
        #pragma unroll
        for (int r = 0; r < 16; r++) { __half2 p = u2h(dppu<0xB1>(h2u(v[r]))); v[r] = __hfma2(v[r], sgn, p); } }
    {   __half2 sgn = __float2half2_rn((lane & 2) ? -1.0f : 1.0f);
        #pragma unroll
        for (int r = 0; r < 16; r++) { __half2 p = u2h(dppu<0x4E>(h2u(v[r]))); v[r] = __hfma2(v[r], sgn, p); } }
    {   __half2 sgn = __float2half2_rn((lane & 4) ? -1.0f : 1.0f);
        #pragma unroll
        for (int r = 0; r < 16; r++) { __half2 p = u2h(xor4_u(h2u(v[r]))); v[r] = __hfma2(v[r], sgn, p); } }
    {   __half2 sgn = __float2half2_rn((lane & 8) ? -1.0f : 1.0f);
        #pragma unroll
        for (int r = 0; r < 16; r++) { __half2 p = u2h(dppu<0x128>(h2u(v[r]))); v[r] = __hfma2(v[r], sgn, p); } }
    {   __half2 sgn = __float2half2_rn((lane & 16) ? -1.0f : 1.0f);
        #pragma unroll
        for (int r = 0; r < 16; r++) v[r] = bfly16_h2(v[r], sgn); }
    {   __half2 sgn = __float2half2_rn((lane & 32) ? -1.0f : 1.0f);
        #pragma unroll
        for (int r = 0; r < 16; r++) v[r] = bfly32_h2(v[r], sgn); }
}

// XOR-permute 4 words by m (0..3): a'[j] = a[j ^ m]
__device__ __forceinline__ void xorperm4(unsigned int a[4], int m) {
    bool s0 = (m & 1) != 0, s1 = (m & 2) != 0;
    unsigned int t0 = s0 ? a[1] : a[0], t1 = s0 ? a[0] : a[1];
    unsigned int t2 = s0 ? a[3] : a[2], t3 = s0 ? a[2] : a[3];
    a[0] = s1 ? t2 : t0; a[1] = s1 ? t3 : t1;
    a[2] = s1 ? t0 : t2; a[3] = s1 ? t1 : t3;
}

// XOR-permute 8 words by m (0..7): a'[j] = a[j ^ m]
__device__ __forceinline__ void xorperm8(unsigned int a[8], int m) {
    bool s0 = (m & 1) != 0, s1 = (m & 2) != 0, s2 = (m & 4) != 0;
    unsigned int b0 = s0 ? a[1] : a[0], b1 = s0 ? a[0] : a[1];
    unsigned int b2 = s0 ? a[3] : a[2], b3 = s0 ? a[2] : a[3];
    unsigned int b4 = s0 ? a[5] : a[4], b5 = s0 ? a[4] : a[5];
    unsigned int b6 = s0 ? a[7] : a[6], b7 = s0 ? a[6] : a[7];
    unsigned int c0 = s1 ? b2 : b0, c1 = s1 ? b3 : b1;
    unsigned int c2 = s1 ? b0 : b2, c3 = s1 ? b1 : b3;
    unsigned int c4 = s1 ? b6 : b4, c5 = s1 ? b7 : b5;
    unsigned int c6 = s1 ? b4 : b6, c7 = s1 ? b5 : b7;
    a[0] = s2 ? c4 : c0; a[1] = s2 ? c5 : c1;
    a[2] = s2 ? c6 : c2; a[3] = s2 ? c7 : c3;
    a[4] = s2 ? c0 : c4; a[5] = s2 ? c1 : c5;
    a[6] = s2 ? c2 : c6; a[7] = s2 ? c3 : c7;
}

// ================= Pass A: f32 in -> (H_l D_l H_l) -> fp16 half2(re,im) ws =================
__global__ __launch_bounds__(256, 4) void pA_kernel(const float* __restrict__ xr,
                                                    const float* __restrict__ xi,
                                                    __half2* __restrict__ ws,
                                                    const float* __restrict__ tptr) {
    const int tid = threadIdx.x, lane = tid & 63, w = tid >> 6;
    const int rt = blockIdx.x * 4 + w;             // (batch*1024 + h) in [0,16384)
    const float tval = tptr[0];
    const int pcl = __popc(lane);
    float cs[5], sn[5];
    #pragma unroll
    for (int k = 0; k < 5; k++) {
        float ang = tval * (float)(10 - 2 * (pcl + k));
        float s, c;
        __sincosf(ang, &s, &c);
        cs[k] = c * 0.03125f;                      // fold 2^-5 for WHT #2
        sn[k] = s * 0.03125f;
    }
    const float* re = xr + (size_t)rt * 1024;
    const float* im = xi + (size_t)rt * 1024;
    float vr[16], vi[16];
    #pragma unroll
    for (int q = 0; q < 2; q++) {
        const int base = q * 512 + lane * 8;
        float4 a0 = *(const float4*)(re + base);
        float4 a1 = *(const float4*)(re + base + 4);
        float4 b0 = *(const float4*)(im + base);
        float4 b1 = *(const float4*)(im + base + 4);
        vr[q*8+0]=a0.x*0.03125f; vr[q*8+1]=a0.y*0.03125f; vr[q*8+2]=a0.z*0.03125f; vr[q*8+3]=a0.w*0.03125f;
        vr[q*8+4]=a1.x*0.03125f; vr[q*8+5]=a1.y*0.03125f; vr[q*8+6]=a1.z*0.03125f; vr[q*8+7]=a1.w*0.03125f;
        vi[q*8+0]=b0.x*0.03125f; vi[q*8+1]=b0.y*0.03125f; vi[q*8+2]=b0.z*0.03125f; vi[q*8+3]=b0.w*0.03125f;
        vi[q*8+4]=b1.x*0.03125f; vi[q*8+5]=b1.y*0.03125f; vi[q*8+6]=b1.z*0.03125f; vi[q*8+7]=b1.w*0.03125f;
    }
    wht16_f32(vr, lane);
    wht16_f32(vi, lane);
    #pragma unroll
    for (int r = 0; r < 16; r++) {
        const int pr = __popc(r);
        float x = vr[r], y = vi[r];
        vr[r] = fmaf(cs[pr], x,  sn[pr] * y);
        vi[r] = fmaf(cs[pr], y, -sn[pr] * x);
    }
    wht16_f32(vr, lane);
    wht16_f32(vi, lane);
    __half2* wp = ws + (size_t)rt * 1024;
    #pragma unroll
    for (int q = 0; q < 2; q++) {
        const int base = q * 512 + lane * 8;
        uint4 u0, u1;
        u0.x = h2u(__floats2half2_rn(vr[q*8+0], vi[q*8+0]));
        u0.y = h2u(__floats2half2_rn(vr[q*8+1], vi[q*8+1]));
        u0.z = h2u(__floats2half2_rn(vr[q*8+2], vi[q*8+2]));
        u0.w = h2u(__floats2half2_rn(vr[q*8+3], vi[q*8+3]));
        u1.x = h2u(__floats2half2_rn(vr[q*8+4], vi[q*8+4]));
        u1.y = h2u(__floats2half2_rn(vr[q*8+5], vi[q*8+5]));
        u1.z = h2u(__floats2half2_rn(vr[q*8+6], vi[q*8+6]));
        u1.w = h2u(__floats2half2_rn(vr[q*8+7], vi[q*8+7]));
        *(uint4*)(wp + base)     = u0;
        *(uint4*)(wp + base + 4) = u1;
    }
}

// ================= Pass B: fp16 ws -> (H_h D_h H_h) -> f32 out =================
// Tile: [1024 h][32 cols] half2 = 128 KiB LDS, 1024 threads (16 waves), 1 block/CU.
// Wave w owns logical cols {w, w+16}. Physical col = logical ^ (h & 31):
// stage rows are 128 B (full line); frag bank = w ^ (lane&31) -> 2 lanes/bank (free).
__global__ __launch_bounds__(1024, 4) void pB_kernel(const __half2* __restrict__ ws,
                                                     float* __restrict__ out,
                                                     const float* __restrict__ tptr) {
    __shared__ unsigned int tile[1024][32];
    const int tid = threadIdx.x, lane = tid & 63, w = tid >> 6;   // w: 0..15

    // XCD-chunked bijective swizzle (512 % 8 == 0)
    int wg  = blockIdx.x;
    int swz = (wg & 7) * 64 + (wg >> 3);
    const int b  = swz >> 5;           // batch 0..15
    const int g  = swz & 31;           // column group 0..31
    const int c0 = g * 32;
    const float tval = tptr[0];

    const int pcl = __popc(lane);
    __half2 c2k[5], s2k[5];
    #pragma unroll
    for (int k = 0; k < 5; k++) {
        float ang = tval * (float)(10 - 2 * (pcl + k));
        float s, c;
        __sincosf(ang, &s, &c);
        c2k[k] = __float2half2_rn(c * 0.03125f);                 // (c', c')
        s2k[k] = __halves2half2(__float2half(s * 0.03125f),
                                __float2half(-s * 0.03125f));    // (s', -s')
    }

    const __half2* src = ws + (size_t)b * DIMN + c0;

    // ---- stage-in: item f=(h, qd 0..7); 128 B contiguous per row (8 lanes) ----
    #pragma unroll
    for (int it = 0; it < 8; it++) {
        int f = it * 1024 + tid;               // 0..8191
        int h = f >> 3, qd = f & 7;
        uint4 a = *(const uint4*)(src + (size_t)h * 1024 + qd * 4);
        unsigned int g4[4] = {a.x, a.y, a.z, a.w};
        int e = h & 31;
        xorperm4(g4, e & 3);
        int dq = qd ^ (e >> 2);
        *(uint4*)&tile[h][dq * 4] = make_uint4(g4[0], g4[1], g4[2], g4[3]);
    }
    __syncthreads();

    // ---- LDS -> regs: logical cols w, w+16; cp = col ^ (lane&31) (2 lanes/bank) ----
    const int el = lane & 31;
    const int cp0 = w ^ el;
    const __half2 sc = __float2half2_rn(0.03125f);
    __half2 v0[16], v1[16];
    #pragma unroll
    for (int r = 0; r < 16; r++) {
        v0[r] = __hmul2(u2h(tile[r * 64 + lane][cp0]),      sc);
        v1[r] = __hmul2(u2h(tile[r * 64 + lane][cp0 ^ 16]), sc);
    }

    // ---- WHT #1 ----
    wht16_h2(v0, lane);
    wht16_h2(v1, lane);

    // ---- rotation (same table for both cols): v' = c2*v + s2*swap16(v) ----
    #pragma unroll
    for (int r = 0; r < 16; r++) {
        const int pr = __popc(r);
        unsigned int u0 = h2u(v0[r]), u1 = h2u(v1[r]);
        __half2 vs0 = u2h((u0 >> 16) | (u0 << 16));
        __half2 vs1 = u2h((u1 >> 16) | (u1 << 16));
        v0[r] = __hfma2(c2k[pr], v0[r], __hmul2(s2k[pr], vs0));
        v1[r] = __hfma2(c2k[pr], v1[r], __hmul2(s2k[pr], vs1));
    }

    // ---- WHT #2 ----
    wht16_h2(v0, lane);
    wht16_h2(v1, lane);

    // ---- regs -> LDS (own columns; disjoint, no pre-barrier) ----
    #pragma unroll
    for (int r = 0; r < 16; r++) {
        tile[r * 64 + lane][cp0]      = h2u(v0[r]);
        tile[r * 64 + lane][cp0 ^ 16] = h2u(v1[r]);
    }
    __syncthreads();

    // ---- stage-out: item f=(h, q8 0..3): 8 half2 -> 8 re + 8 im f32 ----
    float* outR = out + (size_t)b * DIMN + c0;
    float* outI = out + (size_t)16 * DIMN + (size_t)b * DIMN + c0;
    #pragma unroll
    for (int it = 0; it < 4; it++) {
        int f = it * 1024 + tid;               // 0..4095
        int h = f >> 2, q8 = f & 3;
        int e = h & 31;
        int m = e & 3, eh = e >> 2;
        int dq0 = (2 * q8)     ^ eh;
        int dq1 = (2 * q8 + 1) ^ eh;
        uint4 A = *(const uint4*)&tile[h][dq0 * 4];
        uint4 B = *(const uint4*)&tile[h][dq1 * 4];
        unsigned int a4[4] = {A.x, A.y, A.z, A.w};
        unsigned int b4[4] = {B.x, B.y, B.z, B.w};
        xorperm4(a4, m);
        xorperm4(b4, m);
        float4 r0, r1, i0, i1;
        r0.x = __low2float(u2h(a4[0])); i0.x = __high2float(u2h(a4[0]));
        r0.y = __low2float(u2h(a4[1])); i0.y = __high2float(u2h(a4[1]));
        r0.z = __low2float(u2h(a4[2])); i0.z = __high2float(u2h(a4[2]));
        r0.w = __low2float(u2h(a4[3])); i0.w = __high2float(u2h(a4[3]));
        r1.x = __low2float(u2h(b4[0])); i1.x = __high2float(u2h(b4[0]));
        r1.y = __low2float(u2h(b4[1])); i1.y = __high2float(u2h(b4[1]));
        r1.z = __low2float(u2h(b4[2])); i1.z = __high2float(u2h(b4[2]));
        r1.w = __low2float(u2h(b4[3])); i1.w = __high2float(u2h(b4[3]));
        size_t off = (size_t)h * 1024 + q8 * 8;
        *(float4*)(outR + off)     = r0;
        *(float4*)(outR + off + 4) = r1;
        *(float4*)(outI + off)     = i0;
        *(float4*)(outI + off + 4) = i1;
    }
}

// ================= fp32 fallback (3-pass, used only if ws too small) =================
__device__ __forceinline__ void wht10_f4(float4 v[4], int lane) {
    #pragma unroll
    for (int r = 0; r < 4; r++) {
        bf(v[r].x, v[r].y); bf(v[r].z, v[r].w);
        bf(v[r].x, v[r].z); bf(v[r].y, v[r].w);
    }
    #pragma unroll
    for (int m = 1; m <= 32; m <<= 1) {
        float sgn = (lane & m) ? -1.0f : 1.0f;
        #pragma unroll
        for (int r = 0; r < 4; r++) {
            float px = __shfl_xor(v[r].x, m), py = __shfl_xor(v[r].y, m);
            float pz = __shfl_xor(v[r].z, m), pw = __shfl_xor(v[r].w, m);
            v[r].x = fmaf(sgn, v[r].x, px); v[r].y = fmaf(sgn, v[r].y, py);
            v[r].z = fmaf(sgn, v[r].z, pz); v[r].w = fmaf(sgn, v[r].w, pw);
        }
    }
    bf(v[0].x, v[1].x); bf(v[0].y, v[1].y); bf(v[0].z, v[1].z); bf(v[0].w, v[1].w);
    bf(v[2].x, v[3].x); bf(v[2].y, v[3].y); bf(v[2].z, v[3].z); bf(v[2].w, v[3].w);
    bf(v[0].x, v[2].x); bf(v[0].y, v[2].y); bf(v[0].z, v[2].z); bf(v[0].w, v[2].w);
    bf(v[1].x, v[3].x); bf(v[1].y, v[3].y); bf(v[1].z, v[3].z); bf(v[1].w, v[3].w);
}

__global__ __launch_bounds__(256) void pass13_kernel(const float* __restrict__ srcA,
                                                     const float* __restrict__ srcB,
                                                     float* __restrict__ dst) {
    const int tid = threadIdx.x, lane = tid & 63, w = tid >> 6;
    const int rt0 = blockIdx.x * 16 + w * 4;
    const float* src = (rt0 < 16384) ? (srcA + (size_t)rt0 * 1024)
                                     : (srcB + (size_t)(rt0 - 16384) * 1024);
    float* d = dst + (size_t)rt0 * 1024;
    float4 v[4][4];
    #pragma unroll
    for (int rr = 0; rr < 4; rr++)
        #pragma unroll
        for (int r = 0; r < 4; r++)
            v[rr][r] = *(const float4*)(src + rr * 1024 + r * 256 + lane * 4);
    #pragma unroll
    for (int rr = 0; rr < 4; rr++) {
        wht10_f4(v[rr], lane);
        #pragma unroll
        for (int r = 0; r < 4; r++) {
            float4 o;
            o.x = v[rr][r].x * 0.03125f; o.y = v[rr][r].y * 0.03125f;
            o.z = v[rr][r].z * 0.03125f; o.w = v[rr][r].w * 0.03125f;
            *(float4*)(d + rr * 1024 + r * 256 + lane * 4) = o;
        }
    }
}

__global__ __launch_bounds__(256) void pass2f_kernel(float* __restrict__ out,
                                                     const float* __restrict__ tptr) {
    __shared__ __align__(16) float tile[2][1024][8];
    const int tid = threadIdx.x, lane = tid & 63, w = tid >> 6;
    int wg = blockIdx.x;
    int swz = (wg & 7) * 256 + (wg >> 3);
    const int b = swz >> 7, g = swz & 127;
    const int c0 = g * 8;
    const float tval = tptr[0];
    float* baseR = out + (size_t)b * DIMN;
    float* baseI = out + (size_t)16 * DIMN + (size_t)b * DIMN;
    float4 tmp[2][8];
    #pragma unroll
    for (int comp = 0; comp < 2; comp++) {
        const float* src = comp ? baseI : baseR;
        #pragma unroll
        for (int it = 0; it < 8; it++) {
            int f4id = it * 256 + tid;
            int h = f4id >> 1, q = f4id & 1;
            tmp[comp][it] = *(const float4*)(src + (size_t)h * 1024 + c0 + q * 4);
        }
    }
    #pragma unroll
    for (int comp = 0; comp < 2; comp++) {
        #pragma unroll
        for (int it = 0; it < 8; it++) {
            int f4id = it * 256 + tid;
            int h = f4id >> 1, q = f4id & 1;
            int e = (h >> 2) & 7, elo = e & 3;
            float4 val = tmp[comp][it];
            bool s0 = (elo & 1) != 0;
            float x1 = s0 ? val.y : val.x, y1 = s0 ? val.x : val.y;
            float z1 = s0 ? val.w : val.z, w1 = s0 ? val.z : val.w;
            bool s1 = (elo & 2) != 0;
            float x2 = s1 ? z1 : x1, y2 = s1 ? w1 : y1;
            float z2 = s1 ? x1 : z1, w2 = s1 ? y1 : w1;
            int qp = q ^ (e >> 2);
            *(float4*)&tile[comp][h][qp * 4] = make_float4(x2, y2, z2, w2);
        }
    }
    __syncthreads();
    float vr[2][16], vi[2][16];
    #pragma unroll
    for (int r = 0; r < 16; r++) {
        int h = r * 64 + lane;
        int e = (lane >> 2) & 7;
        #pragma unroll
        for (int cc = 0; cc < 2; cc++) {
            int cp = (2 * w + cc) ^ e;
            vr[cc][r] = tile[0][h][cp];
            vi[cc][r] = tile[1][h][cp];
        }
    }
    const int pcl = __popc(lane);
    #pragma unroll
    for (int cc = 0; cc < 2; cc++) {
        wht16_f32(vr[cc], lane);
        wht16_f32(vi[cc], lane);
        const int cg = c0 + 2 * w + cc;
        const int pbase = pcl + __popc(cg);
        float csk[5], snk[5];
        #pragma unroll
        for (int k = 0; k < 5; k++) {
            float ang = tval * (float)(20 - 2 * (pbase + k));
            __sincosf(ang, &snk[k], &csk[k]);
        }
        #pragma unroll
        for (int r = 0; r < 16; r++) {
            const int pr = __popc(r);
            float cv = csk[pr], sv = snk[pr];
            float xr = vr[cc][r] * 0.03125f, xi = vi[cc][r] * 0.03125f;
            vr[cc][r] = fmaf(cv, xr, sv * xi);
            vi[cc][r] = fmaf(cv, xi, -sv * xr);
        }
        wht16_f32(vr[cc], lane);
        wht16_f32(vi[cc], lane);
    }
    #pragma unroll
    for (int r = 0; r < 16; r++) {
        int h = r * 64 + lane;
        int e = (lane >> 2) & 7;
        #pragma unroll
        for (int cc = 0; cc < 2; cc++) {
            int cp = (2 * w + cc) ^ e;
            tile[0][h][cp] = vr[cc][r] * 0.03125f;
            tile[1][h][cp] = vi[cc][r] * 0.03125f;
        }
    }
    __syncthreads();
    #pragma unroll
    for (int comp = 0; comp < 2; comp++) {
        float* dstg = comp ? baseI : baseR;
        #pragma unroll
        for (int it = 0; it < 8; it++) {
            int f4id = it * 256 + tid;
            int h = f4id >> 1, q = f4id & 1;
            int e = (h >> 2) & 7, elo = e & 3;
            int qp = q ^ (e >> 2);
            float4 sv = *(const float4*)&tile[comp][h][qp * 4];
            bool s0 = (elo & 1) != 0;
            float x1 = s0 ? sv.y : sv.x, y1 = s0 ? sv.x : sv.y;
            float z1 = s0 ? sv.w : sv.z, w1 = s0 ? sv.z : sv.w;
            bool s1 = (elo & 2) != 0;
            float x2 = s1 ? z1 : x1, y2 = s1 ? w1 : y1;
            float z2 = s1 ? x1 : z1, w2 = s1 ? y1 : w1;
            *(float4*)(dstg + (size_t)h * 1024 + c0 + q * 4) = make_float4(x2, y2, z2, w2);
        }
    }
}

extern "C" void kernel_launch(void* const* d_in, const int* in_sizes, int n_in,
                              void* d_out, int out_size, void* d_ws, size_t ws_size,
                              hipStream_t stream) {
    const float* xr = (const float*)d_in[0];
    const float* xi = (const float*)d_in[1];
    const float* t  = (const float*)d_in[2];
    float* out = (float*)d_out;

    const size_t need = (size_t)16 * DIMN * sizeof(__half2);  // 64 MiB interleaved
    if (ws_size >= need) {
        __half2* ws = (__half2*)d_ws;
        pA_kernel<<<4096, 256, 0, stream>>>(xr, xi, ws, t);
        pB_kernel<<<512, 1024, 0, stream>>>(ws, out, t);
    } else {
        pass13_kernel<<<2048, 256, 0, stream>>>(xr, xi, out);
        pass2f_kernel<<<2048, 256, 0, stream>>>(out, t);
        pass13_kernel<<<2048, 256, 0, stream>>>(out, out + (size_t)16 * DIMN, out);
    }
}

// Round 11
// 97.187 us; speedup vs baseline: 1.1536x; 1.1536x over previous
//
#include <hip/hip_runtime.h>
#include <hip/hip_fp16.h>
#include <math.h>

#define DIMN (1 << 20)   // 2^20 per batch row
// d_out: [2][16][DIMN] f32.  d_ws: [16][DIMN] half2(re,im) interleaved (64 MiB).
// Factorization: H·D(t)·H = (H_l·D_l·H_l) ⊗ (H_h·D_h·H_h) since
// popc(i) = popc(l)+popc(h) -> D = D_l ⊗ D_h.  Pass A applies the low-bit
// operator along contiguous rows; Pass B the high-bit operator along stride-1024.

typedef unsigned int uint2v __attribute__((ext_vector_type(2)));

// ---------------- bit-cast helpers ----------------
__device__ __forceinline__ unsigned int h2u(__half2 v){ union{__half2 h; unsigned int u;} x; x.h=v; return x.u; }
__device__ __forceinline__ __half2 u2h(unsigned int v){ union{unsigned int u; __half2 h;} x; x.u=v; return x.h; }

__device__ __forceinline__ void bf(float& a, float& b) { float s = a + b; b = a - b; a = s; }

// ---------------- DPP lane-exchange (VALU pipe, not DS) ----------------
template<int CTRL>
__device__ __forceinline__ float dppf(float x) {
    return __int_as_float(__builtin_amdgcn_mov_dpp(__float_as_int(x), CTRL, 0xF, 0xF, true));
}
template<int CTRL>
__device__ __forceinline__ unsigned int dppu(unsigned int x) {
    return (unsigned int)__builtin_amdgcn_mov_dpp((int)x, CTRL, 0xF, 0xF, true);
}
__device__ __forceinline__ float xor4_f(float x) { return dppf<0x1B>(dppf<0x141>(x)); }
__device__ __forceinline__ unsigned int xor4_u(unsigned int x) { return dppu<0x1B>(dppu<0x141>(x)); }

// ---------------- permlane swap butterflies (VALU pipe) ----------------
__device__ __forceinline__ float bfly16_f(float x, float sgn) {
#if __has_builtin(__builtin_amdgcn_permlane16_swap)
    uint2v r = __builtin_amdgcn_permlane16_swap(__float_as_uint(x), __float_as_uint(x), false, false);
    return fmaf(sgn, __uint_as_float(r.y), __uint_as_float(r.x));
#else
    float p = __shfl_xor(x, 16);
    return fmaf(sgn, x, p);
#endif
}
__device__ __forceinline__ float bfly32_f(float x, float sgn) {
#if __has_builtin(__builtin_amdgcn_permlane32_swap)
    uint2v r = __builtin_amdgcn_permlane32_swap(__float_as_uint(x), __float_as_uint(x), false, false);
    return fmaf(sgn, __uint_as_float(r.y), __uint_as_float(r.x));
#else
    float p = __shfl_xor(x, 32);
    return fmaf(sgn, x, p);
#endif
}
__device__ __forceinline__ __half2 bfly16_h2(__half2 x, __half2 sgn) {
#if __has_builtin(__builtin_amdgcn_permlane16_swap)
    uint2v r = __builtin_amdgcn_permlane16_swap(h2u(x), h2u(x), false, false);
    return __hfma2(u2h(r.y), sgn, u2h(r.x));
#else
    __half2 p = u2h((unsigned)__shfl_xor((int)h2u(x), 16));
    return __hfma2(x, sgn, p);
#endif
}
__device__ __forceinline__ __half2 bfly32_h2(__half2 x, __half2 sgn) {
#if __has_builtin(__builtin_amdgcn_permlane32_swap)
    uint2v r = __builtin_amdgcn_permlane32_swap(h2u(x), h2u(x), false, false);
    return __hfma2(u2h(r.y), sgn, u2h(r.x));
#else
    __half2 p = u2h((unsigned)__shfl_xor((int)h2u(x), 32));
    return __hfma2(x, sgn, p);
#endif
}

// ---------------- f32 WHT over 10 bits (all-VALU lane exchange) ----------------
__device__ __forceinline__ void wht16_f32(float v[16], int lane) {
    #pragma unroll
    for (int s = 1; s < 16; s <<= 1)
        #pragma unroll
        for (int r = 0; r < 16; r++)
            if (!(r & s)) bf(v[r], v[r ^ s]);
    {   float sgn = (lane & 1) ? -1.0f : 1.0f;
        #pragma unroll
        for (int r = 0; r < 16; r++) { float p = dppf<0xB1>(v[r]); v[r] = fmaf(sgn, v[r], p); } }
    {   float sgn = (lane & 2) ? -1.0f : 1.0f;
        #pragma unroll
        for (int r = 0; r < 16; r++) { float p = dppf<0x4E>(v[r]); v[r] = fmaf(sgn, v[r], p); } }
    {   float sgn = (lane & 4) ? -1.0f : 1.0f;
        #pragma unroll
        for (int r = 0; r < 16; r++) { float p = xor4_f(v[r]); v[r] = fmaf(sgn, v[r], p); } }
    {   float sgn = (lane & 8) ? -1.0f : 1.0f;
        #pragma unroll
        for (int r = 0; r < 16; r++) { float p = dppf<0x128>(v[r]); v[r] = fmaf(sgn, v[r], p); } }
    {   float sgn = (lane & 16) ? -1.0f : 1.0f;
        #pragma unroll
        for (int r = 0; r < 16; r++) v[r] = bfly16_f(v[r], sgn); }
    {   float sgn = (lane & 32) ? -1.0f : 1.0f;
        #pragma unroll
        for (int r = 0; r < 16; r++) v[r] = bfly32_f(v[r], sgn); }
}

// ---------------- half2 (re,im)-packed WHT over 10 bits ----------------
__device__ __forceinline__ void wht16_h2(__half2 v[16], int lane) {
    #pragma unroll
    for (int s = 1; s < 16; s <<= 1)
        #pragma unroll
        for (int r = 0; r < 16; r++)
            if (!(r & s)) {
                __half2 t = __hadd2(v[r], v[r ^ s]);
                v[r ^ s]  = __hsub2(v[r], v[r ^ s]);
                v[r] = t;
            }
    {   __half2 sgn = __float2half2_rn((lane & 1) ? -1.0f : 1.0f);
        #pragma unroll
        for (int r = 0; r < 16; r++) { __half2 p = u2h(dppu<0xB1>(h2u(v[r]))); v[r] = __hfma2(v[r], sgn, p); } }
    {   __half2 sgn = __float2half2_rn((lane & 2) ? -1.0f : 1.0f);
        #pragma unroll
        for (int r = 0; r < 16; r++) { __half2 p = u2h(dppu<0x4E>(h2u(v[r]))); v[r] = __hfma2(v[r], sgn, p); } }
    {   __half2 sgn = __float2half2_rn((lane & 4) ? -1.0f : 1.0f);
        #pragma unroll
        for (int r = 0; r < 16; r++) { __half2 p = u2h(xor4_u(h2u(v[r]))); v[r] = __hfma2(v[r], sgn, p); } }
    {   __half2 sgn = __float2half2_rn((lane & 8) ? -1.0f : 1.0f);
        #pragma unroll
        for (int r = 0; r < 16; r++) { __half2 p = u2h(dppu<0x128>(h2u(v[r]))); v[r] = __hfma2(v[r], sgn, p); } }
    {   __half2 sgn = __float2half2_rn((lane & 16) ? -1.0f : 1.0f);
        #pragma unroll
        for (int r = 0; r < 16; r++) v[r] = bfly16_h2(v[r], sgn); }
    {   __half2 sgn = __float2half2_rn((lane & 32) ? -1.0f : 1.0f);
        #pragma unroll
        for (int r = 0; r < 16; r++) v[r] = bfly32_h2(v[r], sgn); }
}

// XOR-permute 4 words by m (0..3): a'[j] = a[j ^ m]
__device__ __forceinline__ void xorperm4(unsigned int a[4], int m) {
    bool s0 = (m & 1) != 0, s1 = (m & 2) != 0;
    unsigned int t0 = s0 ? a[1] : a[0], t1 = s0 ? a[0] : a[1];
    unsigned int t2 = s0 ? a[3] : a[2], t3 = s0 ? a[2] : a[3];
    a[0] = s1 ? t2 : t0; a[1] = s1 ? t3 : t1;
    a[2] = s1 ? t0 : t2; a[3] = s1 ? t1 : t3;
}

// XOR-permute 8 words by m (0..7): a'[j] = a[j ^ m]
__device__ __forceinline__ void xorperm8(unsigned int a[8], int m) {
    bool s0 = (m & 1) != 0, s1 = (m & 2) != 0, s2 = (m & 4) != 0;
    unsigned int b0 = s0 ? a[1] : a[0], b1 = s0 ? a[0] : a[1];
    unsigned int b2 = s0 ? a[3] : a[2], b3 = s0 ? a[2] : a[3];
    unsigned int b4 = s0 ? a[5] : a[4], b5 = s0 ? a[4] : a[5];
    unsigned int b6 = s0 ? a[7] : a[6], b7 = s0 ? a[6] : a[7];
    unsigned int c0 = s1 ? b2 : b0, c1 = s1 ? b3 : b1;
    unsigned int c2 = s1 ? b0 : b2, c3 = s1 ? b1 : b3;
    unsigned int c4 = s1 ? b6 : b4, c5 = s1 ? b7 : b5;
    unsigned int c6 = s1 ? b4 : b6, c7 = s1 ? b5 : b7;
    a[0] = s2 ? c4 : c0; a[1] = s2 ? c5 : c1;
    a[2] = s2 ? c6 : c2; a[3] = s2 ? c7 : c3;
    a[4] = s2 ? c0 : c4; a[5] = s2 ? c1 : c5;
    a[6] = s2 ? c2 : c6; a[7] = s2 ? c3 : c7;
}

// ================= Pass A: f32 in -> (H_l D_l H_l) -> fp16 half2(re,im) ws =================
// Element l = q*512 + lane*8 + s (reg r = q*8+s); popc(l) = popc(lane) + popc(r).
__global__ __launch_bounds__(256, 4) void pA_kernel(const float* __restrict__ xr,
                                                    const float* __restrict__ xi,
                                                    __half2* __restrict__ ws,
                                                    const float* __restrict__ tptr) {
    const int tid = threadIdx.x, lane = tid & 63, w = tid >> 6;
    const int rt = blockIdx.x * 4 + w;             // (batch*1024 + h) in [0,16384)
    const float tval = tptr[0];
    const int pcl = __popc(lane);
    float cs[5], sn[5];
    #pragma unroll
    for (int k = 0; k < 5; k++) {
        float ang = tval * (float)(10 - 2 * (pcl + k));
        float s, c;
        __sincosf(ang, &s, &c);
        cs[k] = c * 0.03125f;                      // fold 2^-5 for WHT #2
        sn[k] = s * 0.03125f;
    }
    const float* re = xr + (size_t)rt * 1024;
    const float* im = xi + (size_t)rt * 1024;
    float vr[16], vi[16];
    #pragma unroll
    for (int q = 0; q < 2; q++) {
        const int base = q * 512 + lane * 8;
        float4 a0 = *(const float4*)(re + base);
        float4 a1 = *(const float4*)(re + base + 4);
        float4 b0 = *(const float4*)(im + base);
        float4 b1 = *(const float4*)(im + base + 4);
        vr[q*8+0]=a0.x*0.03125f; vr[q*8+1]=a0.y*0.03125f; vr[q*8+2]=a0.z*0.03125f; vr[q*8+3]=a0.w*0.03125f;
        vr[q*8+4]=a1.x*0.03125f; vr[q*8+5]=a1.y*0.03125f; vr[q*8+6]=a1.z*0.03125f; vr[q*8+7]=a1.w*0.03125f;
        vi[q*8+0]=b0.x*0.03125f; vi[q*8+1]=b0.y*0.03125f; vi[q*8+2]=b0.z*0.03125f; vi[q*8+3]=b0.w*0.03125f;
        vi[q*8+4]=b1.x*0.03125f; vi[q*8+5]=b1.y*0.03125f; vi[q*8+6]=b1.z*0.03125f; vi[q*8+7]=b1.w*0.03125f;
    }
    wht16_f32(vr, lane);
    wht16_f32(vi, lane);
    #pragma unroll
    for (int r = 0; r < 16; r++) {
        const int pr = __popc(r);                  // popc of element bits in regs
        float x = vr[r], y = vi[r];
        vr[r] = fmaf(cs[pr], x,  sn[pr] * y);      // c*xr + s*xi
        vi[r] = fmaf(cs[pr], y, -sn[pr] * x);      // c*xi - s*xr
    }
    wht16_f32(vr, lane);
    wht16_f32(vi, lane);
    __half2* wp = ws + (size_t)rt * 1024;
    #pragma unroll
    for (int q = 0; q < 2; q++) {
        const int base = q * 512 + lane * 8;
        uint4 u0, u1;
        u0.x = h2u(__floats2half2_rn(vr[q*8+0], vi[q*8+0]));
        u0.y = h2u(__floats2half2_rn(vr[q*8+1], vi[q*8+1]));
        u0.z = h2u(__floats2half2_rn(vr[q*8+2], vi[q*8+2]));
        u0.w = h2u(__floats2half2_rn(vr[q*8+3], vi[q*8+3]));
        u1.x = h2u(__floats2half2_rn(vr[q*8+4], vi[q*8+4]));
        u1.y = h2u(__floats2half2_rn(vr[q*8+5], vi[q*8+5]));
        u1.z = h2u(__floats2half2_rn(vr[q*8+6], vi[q*8+6]));
        u1.w = h2u(__floats2half2_rn(vr[q*8+7], vi[q*8+7]));
        *(uint4*)(wp + base)     = u0;
        *(uint4*)(wp + base + 4) = u1;
    }
}

// ================= Pass B: fp16 ws -> (H_h D_h H_h) -> f32 out =================
// Tile: [1024 h][16 cols] half2 = 64 KiB LDS, 512 threads, 2 blocks/CU.
// Wave w owns logical cols {w, w+8}. Physical col = logical ^ ((h>>2)&15).
// Rotation depends only on popc(h) -> one 5-entry table for both columns.
__global__ __launch_bounds__(512, 4) void pB_kernel(const __half2* __restrict__ ws,
                                                    float* __restrict__ out,
                                                    const float* __restrict__ tptr) {
    __shared__ unsigned int tile[1024][16];
    const int tid = threadIdx.x, lane = tid & 63, w = tid >> 6;

    // XCD-chunked bijective swizzle (1024 % 8 == 0)
    int wg  = blockIdx.x;
    int swz = (wg & 7) * 128 + (wg >> 3);
    const int b  = swz >> 6;           // batch 0..15
    const int g  = swz & 63;           // column group 0..63
    const int c0 = g * 16;
    const float tval = tptr[0];

    const int pcl = __popc(lane);
    __half2 c2k[5], s2k[5];
    #pragma unroll
    for (int k = 0; k < 5; k++) {
        float ang = tval * (float)(10 - 2 * (pcl + k));
        float s, c;
        __sincosf(ang, &s, &c);
        c2k[k] = __float2half2_rn(c * 0.03125f);                 // (c', c')
        s2k[k] = __halves2half2(__float2half(s * 0.03125f),
                                __float2half(-s * 0.03125f));    // (s', -s')
    }

    const __half2* src = ws + (size_t)b * DIMN + c0;

    // ---- stage-in: item f=(h, quad); 64 B contiguous per row, 16 rows/wave-load ----
    #pragma unroll
    for (int it = 0; it < 8; it++) {
        int f = it * 512 + tid;                // 0..4095
        int h = f >> 2, qd = f & 3;
        uint4 a = *(const uint4*)(src + (size_t)h * 1024 + qd * 4);
        unsigned int g4[4] = {a.x, a.y, a.z, a.w};
        int e = (h >> 2) & 15;
        xorperm4(g4, e & 3);
        int dq = qd ^ (e >> 2);
        *(uint4*)&tile[h][dq * 4] = make_uint4(g4[0], g4[1], g4[2], g4[3]);
    }
    __syncthreads();

    // ---- LDS -> regs: logical cols w, w+8 (2 lanes/bank, conflict-free) ----
    const int e4 = (lane >> 2) & 15;
    const int cp0 = w ^ e4;
    const __half2 sc = __float2half2_rn(0.03125f);
    __half2 v0[16], v1[16];
    #pragma unroll
    for (int r = 0; r < 16; r++) {
        v0[r] = __hmul2(u2h(tile[r * 64 + lane][cp0]),     sc);
        v1[r] = __hmul2(u2h(tile[r * 64 + lane][cp0 ^ 8]), sc);
    }

    // ---- WHT #1 ----
    wht16_h2(v0, lane);
    wht16_h2(v1, lane);

    // ---- rotation (same table for both cols): v' = c2*v + s2*swap16(v) ----
    #pragma unroll
    for (int r = 0; r < 16; r++) {
        const int pr = __popc(r);
        unsigned int u0 = h2u(v0[r]), u1 = h2u(v1[r]);
        __half2 vs0 = u2h((u0 >> 16) | (u0 << 16));
        __half2 vs1 = u2h((u1 >> 16) | (u1 << 16));
        v0[r] = __hfma2(c2k[pr], v0[r], __hmul2(s2k[pr], vs0));
        v1[r] = __hfma2(c2k[pr], v1[r], __hmul2(s2k[pr], vs1));
    }

    // ---- WHT #2 ----
    wht16_h2(v0, lane);
    wht16_h2(v1, lane);

    // ---- regs -> LDS (own columns; disjoint, no pre-barrier) ----
    #pragma unroll
    for (int r = 0; r < 16; r++) {
        tile[r * 64 + lane][cp0]     = h2u(v0[r]);
        tile[r * 64 + lane][cp0 ^ 8] = h2u(v1[r]);
    }
    __syncthreads();

    // ---- stage-out: unpack half2 -> f32 re/im planes of d_out ----
    float* outR = out + (size_t)b * DIMN + c0;
    float* outI = out + (size_t)16 * DIMN + (size_t)b * DIMN + c0;
    #pragma unroll
    for (int it = 0; it < 4; it++) {
        int f = it * 512 + tid;                // 0..2047
        int h = f >> 1, q8 = f & 1;
        int e = (h >> 2) & 15;
        int base = (q8 ^ (e >> 3)) * 8;
        uint4 u0 = *(const uint4*)&tile[h][base];
        uint4 u1 = *(const uint4*)&tile[h][base + 4];
        unsigned int w8[8] = {u0.x, u0.y, u0.z, u0.w, u1.x, u1.y, u1.z, u1.w};
        xorperm8(w8, e & 7);
        float4 r0, r1, i0, i1;
        r0.x = __low2float(u2h(w8[0])); i0.x = __high2float(u2h(w8[0]));
        r0.y = __low2float(u2h(w8[1])); i0.y = __high2float(u2h(w8[1]));
        r0.z = __low2float(u2h(w8[2])); i0.z = __high2float(u2h(w8[2]));
        r0.w = __low2float(u2h(w8[3])); i0.w = __high2float(u2h(w8[3]));
        r1.x = __low2float(u2h(w8[4])); i1.x = __high2float(u2h(w8[4]));
        r1.y = __low2float(u2h(w8[5])); i1.y = __high2float(u2h(w8[5]));
        r1.z = __low2float(u2h(w8[6])); i1.z = __high2float(u2h(w8[6]));
        r1.w = __low2float(u2h(w8[7])); i1.w = __high2float(u2h(w8[7]));
        size_t off = (size_t)h * 1024 + q8 * 8;
        *(float4*)(outR + off)     = r0;
        *(float4*)(outR + off + 4) = r1;
        *(float4*)(outI + off)     = i0;
        *(float4*)(outI + off + 4) = i1;
    }
}

// ================= fp32 fallback (3-pass, used only if ws too small) =================
__device__ __forceinline__ void wht10_f4(float4 v[4], int lane) {
    #pragma unroll
    for (int r = 0; r < 4; r++) {
        bf(v[r].x, v[r].y); bf(v[r].z, v[r].w);
        bf(v[r].x, v[r].z); bf(v[r].y, v[r].w);
    }
    #pragma unroll
    for (int m = 1; m <= 32; m <<= 1) {
        float sgn = (lane & m) ? -1.0f : 1.0f;
        #pragma unroll
        for (int r = 0; r < 4; r++) {
            float px = __shfl_xor(v[r].x, m), py = __shfl_xor(v[r].y, m);
            float pz = __shfl_xor(v[r].z, m), pw = __shfl_xor(v[r].w, m);
            v[r].x = fmaf(sgn, v[r].x, px); v[r].y = fmaf(sgn, v[r].y, py);
            v[r].z = fmaf(sgn, v[r].z, pz); v[r].w = fmaf(sgn, v[r].w, pw);
        }
    }
    bf(v[0].x, v[1].x); bf(v[0].y, v[1].y); bf(v[0].z, v[1].z); bf(v[0].w, v[1].w);
    bf(v[2].x, v[3].x); bf(v[2].y, v[3].y); bf(v[2].z, v[3].z); bf(v[2].w, v[3].w);
    bf(v[0].x, v[2].x); bf(v[0].y, v[2].y); bf(v[0].z, v[2].z); bf(v[0].w, v[2].w);
    bf(v[1].x, v[3].x); bf(v[1].y, v[3].y); bf(v[1].z, v[3].z); bf(v[1].w, v[3].w);
}

__global__ __launch_bounds__(256) void pass13_kernel(const float* __restrict__ srcA,
                                                     const float* __restrict__ srcB,
                                                     float* __restrict__ dst) {
    const int tid = threadIdx.x, lane = tid & 63, w = tid >> 6;
    const int rt0 = blockIdx.x * 16 + w * 4;
    const float* src = (rt0 < 16384) ? (srcA + (size_t)rt0 * 1024)
                                     : (srcB + (size_t)(rt0 - 16384) * 1024);
    float* d = dst + (size_t)rt0 * 1024;
    float4 v[4][4];
    #pragma unroll
    for (int rr = 0; rr < 4; rr++)
        #pragma unroll
        for (int r = 0; r < 4; r++)
            v[rr][r] = *(const float4*)(src + rr * 1024 + r * 256 + lane * 4);
    #pragma unroll
    for (int rr = 0; rr < 4; rr++) {
        wht10_f4(v[rr], lane);
        #pragma unroll
        for (int r = 0; r < 4; r++) {
            float4 o;
            o.x = v[rr][r].x * 0.03125f; o.y = v[rr][r].y * 0.03125f;
            o.z = v[rr][r].z * 0.03125f; o.w = v[rr][r].w * 0.03125f;
            *(float4*)(d + rr * 1024 + r * 256 + lane * 4) = o;
        }
    }
}

__global__ __launch_bounds__(256) void pass2f_kernel(float* __restrict__ out,
                                                     const float* __restrict__ tptr) {
    __shared__ __align__(16) float tile[2][1024][8];
    const int tid = threadIdx.x, lane = tid & 63, w = tid >> 6;
    int wg = blockIdx.x;
    int swz = (wg & 7) * 256 + (wg >> 3);
    const int b = swz >> 7, g = swz & 127;
    const int c0 = g * 8;
    const float tval = tptr[0];
    float* baseR = out + (size_t)b * DIMN;
    float* baseI = out + (size_t)16 * DIMN + (size_t)b * DIMN;
    float4 tmp[2][8];
    #pragma unroll
    for (int comp = 0; comp < 2; comp++) {
        const float* src = comp ? baseI : baseR;
        #pragma unroll
        for (int it = 0; it < 8; it++) {
            int f4id = it * 256 + tid;
            int h = f4id >> 1, q = f4id & 1;
            tmp[comp][it] = *(const float4*)(src + (size_t)h * 1024 + c0 + q * 4);
        }
    }
    #pragma unroll
    for (int comp = 0; comp < 2; comp++) {
        #pragma unroll
        for (int it = 0; it < 8; it++) {
            int f4id = it * 256 + tid;
            int h = f4id >> 1, q = f4id & 1;
            int e = (h >> 2) & 7, elo = e & 3;
            float4 val = tmp[comp][it];
            bool s0 = (elo & 1) != 0;
            float x1 = s0 ? val.y : val.x, y1 = s0 ? val.x : val.y;
            float z1 = s0 ? val.w : val.z, w1 = s0 ? val.z : val.w;
            bool s1 = (elo & 2) != 0;
            float x2 = s1 ? z1 : x1, y2 = s1 ? w1 : y1;
            float z2 = s1 ? x1 : z1, w2 = s1 ? y1 : w1;
            int qp = q ^ (e >> 2);
            *(float4*)&tile[comp][h][qp * 4] = make_float4(x2, y2, z2, w2);
        }
    }
    __syncthreads();
    float vr[2][16], vi[2][16];
    #pragma unroll
    for (int r = 0; r < 16; r++) {
        int h = r * 64 + lane;
        int e = (lane >> 2) & 7;
        #pragma unroll
        for (int cc = 0; cc < 2; cc++) {
            int cp = (2 * w + cc) ^ e;
            vr[cc][r] = tile[0][h][cp];
            vi[cc][r] = tile[1][h][cp];
        }
    }
    const int pcl = __popc(lane);
    #pragma unroll
    for (int cc = 0; cc < 2; cc++) {
        wht16_f32(vr[cc], lane);
        wht16_f32(vi[cc], lane);
        const int cg = c0 + 2 * w + cc;
        const int pbase = pcl + __popc(cg);
        float csk[5], snk[5];
        #pragma unroll
        for (int k = 0; k < 5; k++) {
            float ang = tval * (float)(20 - 2 * (pbase + k));
            __sincosf(ang, &snk[k], &csk[k]);
        }
        #pragma unroll
        for (int r = 0; r < 16; r++) {
            const int pr = __popc(r);
            float cv = csk[pr], sv = snk[pr];
            float xr = vr[cc][r] * 0.03125f, xi = vi[cc][r] * 0.03125f;
            vr[cc][r] = fmaf(cv, xr, sv * xi);
            vi[cc][r] = fmaf(cv, xi, -sv * xr);
        }
        wht16_f32(vr[cc], lane);
        wht16_f32(vi[cc], lane);
    }
    #pragma unroll
    for (int r = 0; r < 16; r++) {
        int h = r * 64 + lane;
        int e = (lane >> 2) & 7;
        #pragma unroll
        for (int cc = 0; cc < 2; cc++) {
            int cp = (2 * w + cc) ^ e;
            tile[0][h][cp] = vr[cc][r] * 0.03125f;
            tile[1][h][cp] = vi[cc][r] * 0.03125f;
        }
    }
    __syncthreads();
    #pragma unroll
    for (int comp = 0; comp < 2; comp++) {
        float* dstg = comp ? baseI : baseR;
        #pragma unroll
        for (int it = 0; it < 8; it++) {
            int f4id = it * 256 + tid;
            int h = f4id >> 1, q = f4id & 1;
            int e = (h >> 2) & 7, elo = e & 3;
            int qp = q ^ (e >> 2);
            float4 sv = *(const float4*)&tile[comp][h][qp * 4];
            bool s0 = (elo & 1) != 0;
            float x1 = s0 ? sv.y : sv.x, y1 = s0 ? sv.x : sv.y;
            float z1 = s0 ? sv.w : sv.z, w1 = s0 ? sv.z : sv.w;
            bool s1 = (elo & 2) != 0;
            float x2 = s1 ? z1 : x1, y2 = s1 ? w1 : y1;
            float z2 = s1 ? x1 : z1, w2 = s1 ? y1 : w1;
            *(float4*)(dstg + (size_t)h * 1024 + c0 + q * 4) = make_float4(x2, y2, z2, w2);
        }
    }
}

extern "C" void kernel_launch(void* const* d_in, const int* in_sizes, int n_in,
                              void* d_out, int out_size, void* d_ws, size_t ws_size,
                              hipStream_t stream) {
    const float* xr = (const float*)d_in[0];
    const float* xi = (const float*)d_in[1];
    const float* t  = (const float*)d_in[2];
    float* out = (float*)d_out;

    const size_t need = (size_t)16 * DIMN * sizeof(__half2);  // 64 MiB interleaved
    if (ws_size >= need) {
        __half2* ws = (__half2*)d_ws;
        pA_kernel<<<4096, 256, 0, stream>>>(xr, xi, ws, t);
        pB_kernel<<<1024, 512, 0, stream>>>(ws, out, t);
    } else {
        pass13_kernel<<<2048, 256, 0, stream>>>(xr, xi, out);
        pass2f_kernel<<<2048, 256, 0, stream>>>(out, t);
        pass13_kernel<<<2048, 256, 0, stream>>>(out, out + (size_t)16 * DIMN, out);
    }
}